// Round 7
// baseline (3040.360 us; speedup 1.0000x reference)
//
#include <hip/hip_runtime.h>
#include <hip/hip_fp16.h>

typedef unsigned int u32;
typedef unsigned short u16;
typedef _Float16 half2v __attribute__((ext_vector_type(2)));
typedef u32 u32x4 __attribute__((ext_vector_type(4)));
typedef u32 u32x2 __attribute__((ext_vector_type(2)));

#define N_UNITS 512
#define N_ORDER 256
#define N_T     1024
#define N_B     64
#define KWG     4
#define PKT_STRIDE 288   // dwords per (parity,b,q) packet: 128 m + 128 h + 4 u + pad

__device__ inline float dot2f(u32 a, u32 b, float acc) {
    return __builtin_amdgcn_fdot2(__builtin_bit_cast(half2v, a),
                                  __builtin_bit_cast(half2v, b), acc, false);
}
__device__ inline u16 f2h_bits(float v) {
    _Float16 f = (_Float16)v;
    return __builtin_bit_cast(u16, f);
}
__device__ inline float hbits2f(u32 dw) {
    u16 s = (u16)(dw & 0xFFFFu);
    _Float16 f = __builtin_bit_cast(_Float16, s);
    return (float)f;
}
__device__ inline u32 pack_h2(float a, float b) {
    return (u32)f2h_bits(a) | ((u32)f2h_bits(b) << 16);
}
// Wide coherent packet ops (R6-proven): ONE request at the coherence point.
// Per-dword atomicity of aligned dwordx2/x4 is architectural; each dword
// self-validates via the epoch in its high16.
__device__ inline u32x4 aload4(const u32* p) {
    u32x4 r;
    asm volatile("global_load_dwordx4 %0, %1, off sc0 sc1\n\ts_waitcnt vmcnt(0)"
                 : "=&v"(r) : "v"(p) : "memory");
    return r;
}
__device__ inline void astore2(u32* p, u32 a, u32 b) {
    u32x2 v; v.x = a; v.y = b;
    asm volatile("global_store_dwordx2 %0, %1, off sc0 sc1"
                 :: "v"(p), "v"(v) : "memory");
}
__device__ inline void astore4(u32* p, u32 a, u32 b, u32 c, u32 d) {
    u32x4 v; v.x = a; v.y = b; v.z = c; v.w = d;
    asm volatile("global_store_dwordx4 %0, %1, off sc0 sc1"
                 :: "v"(p), "v"(v) : "memory");
}

// hk2[kk][c] = half2(hk[2kk][c], hk[2kk+1][c]),  kk<256, c<512
__global__ __launch_bounds__(256)
void prep_hk(const float* __restrict__ hk, u32* __restrict__ hk2) {
    int tid = blockIdx.x * 256 + threadIdx.x;   // 131072 total
    int kk = tid >> 9, c = tid & 511;
    hk2[tid] = pack_h2(hk[(2 * kk) * 512 + c], hk[(2 * kk + 1) * 512 + c]);
}

// AMK = mk + AT@mk  (fp16, j-pair packed);  BMK = BT@mk (fp32)
__global__ __launch_bounds__(512)
void prep_amk(const float* __restrict__ mk, const float* __restrict__ at,
              const float* __restrict__ bt,
              u32* __restrict__ amk2, float* __restrict__ bmk) {
    int bj = blockIdx.x, c = threadIdx.x;
    if (bj < 128) {
        int j0 = 2 * bj, j1 = j0 + 1;
        float a0 = mk[j0 * 512 + c];
        float a1 = mk[j1 * 512 + c];
        #pragma unroll 8
        for (int k = 0; k < 256; ++k) {
            float w = mk[k * 512 + c];
            a0 = fmaf(at[j0 * 256 + k], w, a0);
            a1 = fmaf(at[j1 * 256 + k], w, a1);
        }
        amk2[bj * 512 + c] = pack_h2(a0, a1);
    } else {
        float s = 0.f;
        #pragma unroll 8
        for (int k = 0; k < 256; ++k) s = fmaf(bt[k], mk[k * 512 + c], s);
        bmk[c] = s;
    }
}

// K=4 WGs per batch; grid=256 (1 WG/CU). g: b=g&63, q=g>>6 (same XCD mod-8).
// WG q owns h cols [128q,128q+128), m cols [64q,64q+64).
// Round-7 deltas vs R6 (2760us), same coherence-request mechanism:
//  * producer packing: h 128xdword -> 64xdwordx2 (shfl pair), m 64xdwordx2 ->
//    32xdwordx4 (two shfls). Producer requests 193 -> 97 per WG/step.
//  * u per-wave publish: waves 0/1 each store their reduced u-pair right after
//    their shfl-reduce (dwordx2 at +256/+258). B3 + tid0 funnel DELETED.
//    Consumer u-poll is one dwordx4 (request count unchanged). Local handoff
//    via parity-double-buffered upw/upart (WAR-safe by barrier collectivity).
//  * consumer LDS writes packed to u32 (R2-verified code).
__global__ __launch_bounds__(512, 2)
void lmu_main(const float* __restrict__ x, const float* __restrict__ ie,
              const float* __restrict__ he, const float* __restrict__ me,
              const float* __restrict__ ik, const float* __restrict__ bt,
              const float* __restrict__ at,
              const u32* __restrict__ hk2, const u32* __restrict__ amk2,
              const float* __restrict__ bmk,
              u32* __restrict__ pkt, float* __restrict__ out) {
    __shared__ float xs[N_T];
    __shared__ float he_sl[128], ik_sl[128], bmk_sl[128];
    __shared__ float me_sl[64], bt_sl[64];
    __shared__ __align__(8) u16 h_h16[N_UNITS];     // full h, fp16
    __shared__ __align__(8) u16 m_hi16[N_ORDER], m_lo16[N_ORDER];
    __shared__ __align__(8) float mf[N_ORDER];      // full m, fp32(-ish)
    __shared__ float zbuf[512], ampart[512];
    __shared__ float upart[2][4];                   // [parity][peer q] (own slot stays 0)
    __shared__ float upw[2][2];                     // [parity][own wave 0/1]

    const int tid = threadIdx.x;
    const int g   = blockIdx.x;
    const int b   = g & 63;
    const int q   = g >> 6;
    const int kg  = tid >> 7;        // 0..3 (hk/AMK k-group)
    const int cl  = tid & 127;       // col within own h slice
    const int kg8 = tid >> 6;        // 0..7 (AT k-group)
    const int jl  = tid & 63;
    const int J   = 64 * q + jl;
    const int lane = tid & 63;

    // ---- preload LDS ----
    for (int i = tid; i < N_T; i += 512) xs[i] = x[b * N_T + i];
    if (tid < 128) {
        he_sl[tid]  = he[128 * q + tid];
        ik_sl[tid]  = ik[128 * q + tid];
        bmk_sl[tid] = bmk[128 * q + tid];
    }
    if (tid < 64) { me_sl[tid] = me[J]; bt_sl[tid] = bt[J]; }
    h_h16[tid] = 0;
    if (tid < 256) { m_hi16[tid] = 0; m_lo16[tid] = 0; mf[tid] = 0.f; }
    if (tid < 8) (&upart[0][0])[tid] = 0.f;
    if (tid < 4) (&upw[0][0])[tid] = 0.f;
    const float ie0 = ie[0];

    // ---- weights into registers (once) ----
    u32 hk_w[64];
    #pragma unroll
    for (int i = 0; i < 64; ++i)
        hk_w[i] = hk2[(size_t)(64 * kg + i) * 512 + 128 * q + cl];
    u32 amk_w[32];
    #pragma unroll
    for (int i = 0; i < 32; ++i)
        amk_w[i] = amk2[(size_t)(32 * kg + i) * 512 + 128 * q + cl];
    float at_w[32];
    #pragma unroll
    for (int i = 0; i < 32; ++i)
        at_w[i] = at[(size_t)(32 * kg8 + i) * 256 + J];

    __syncthreads();

    const u32* h2u   = reinterpret_cast<const u32*>(h_h16);
    const u32* m_hi2 = reinterpret_cast<const u32*>(m_hi16);
    const u32* m_lo2 = reinterpret_cast<const u32*>(m_lo16);
    float* outb = out + (size_t)b * N_T * N_UNITS;

    for (int t = 0; t < N_T; ++t) {
        const int pc = t & 1;   // upart/upw parity consumed this step

        // ---- consume peers' packets (h_{t-1}, m_{t-1}, u-partials) ----
        if (t > 0) {
            const u32 ep  = (u32)t;
            const int par = (t - 1) & 1;
            if (tid < 195) {
                int pi = (tid < 192) ? (tid >> 6) : (tid - 192);
                int q2 = pi + (pi >= q ? 1 : 0);
                const u32* base = pkt + (size_t)(par * 256 + b * 4 + q2) * PKT_STRIDE;
                if (tid < 192) {
                    int i = tid & 63;
                    u32 d0, d1, d2, d3;
                    for (;;) {
                        u32x4 dv = aload4(base + 4 * i);
                        d0 = dv.x; d1 = dv.y; d2 = dv.z; d3 = dv.w;
                        if (((((d0 >> 16) ^ ep) | ((d1 >> 16) ^ ep)) |
                             (((d2 >> 16) ^ ep) | ((d3 >> 16) ^ ep))) == 0) break;
                    }
                    if (i < 32) {          // m: j = 2i, 2i+1 (hi,lo dword pairs)
                        int idx = 64 * q2 + 2 * i;       // even
                        float2 v;
                        v.x = hbits2f(d0) + hbits2f(d1);
                        v.y = hbits2f(d2) + hbits2f(d3);
                        *reinterpret_cast<float2*>(mf + idx) = v;
                        reinterpret_cast<u32*>(m_hi16)[idx >> 1] = (d0 & 0xFFFFu) | (d2 << 16);
                        reinterpret_cast<u32*>(m_lo16)[idx >> 1] = (d1 & 0xFFFFu) | (d3 << 16);
                    } else {               // h: c = 4i-128 .. +3
                        int i0 = (128 * q2 + 4 * i - 128) >> 1;
                        u32* hhp = reinterpret_cast<u32*>(h_h16);
                        hhp[i0]     = (d0 & 0xFFFFu) | (d1 << 16);
                        hhp[i0 + 1] = (d2 & 0xFFFFu) | (d3 << 16);
                    }
                } else {                   // u: 2 per-wave hi/lo pairs, one x4
                    u32 d0, d1, d2, d3;
                    for (;;) {
                        u32x4 dv = aload4(base + 256);
                        d0 = dv.x; d1 = dv.y; d2 = dv.z; d3 = dv.w;
                        if (((((d0 >> 16) ^ ep) | ((d1 >> 16) ^ ep)) |
                             (((d2 >> 16) ^ ep) | ((d3 >> 16) ^ ep))) == 0) break;
                    }
                    upart[pc][q2] = (hbits2f(d0) + hbits2f(d1))
                                  + (hbits2f(d2) + hbits2f(d3));
                }
            }
        }
        __syncthreads();                                   // B1

        // ---- z partials (old h, old m) + AT partials (old m) — all local ----
        {
            float z = 0.f;
            #pragma unroll
            for (int i = 0; i < 64; ++i)
                z = dot2f(h2u[64 * kg + i], hk_w[i], z);
            #pragma unroll
            for (int i = 0; i < 32; ++i) {
                u32 w = amk_w[i];
                z = dot2f(m_hi2[32 * kg + i], w, z);
                z = dot2f(m_lo2[32 * kg + i], w, z);
            }
            zbuf[tid] = z;
            float am = 0.f;
            #pragma unroll
            for (int i = 0; i < 32; ++i)
                am = fmaf(mf[32 * kg8 + i], at_w[i], am);
            ampart[tid] = am;
        }
        __syncthreads();                                   // B2

        // ---- finalize: u, m_new slice, h_new slice ----
        float u = 0.f, mnew = 0.f, hnew = 0.f;
        u16 mhi_b = 0, mlo_b = 0;
        if (tid < 128)
            u = ((upart[pc][0] + upart[pc][1]) + (upart[pc][2] + upart[pc][3]))
              + (upw[pc][0] + upw[pc][1]) + xs[t] * ie0;
        if (tid < 64) {
            mnew = mf[J] + u * bt_sl[tid];
            #pragma unroll
            for (int gi = 0; gi < 8; ++gi) mnew += ampart[tid + 64 * gi];
            _Float16 hi = (_Float16)mnew;
            float lo = mnew - (float)hi;
            mhi_b = __builtin_bit_cast(u16, hi);
            mlo_b = f2h_bits(lo);
            mf[J] = mnew;            // own slice stays exact fp32
            m_hi16[J] = mhi_b;
            m_lo16[J] = mlo_b;
        }
        if (tid < 128) {
            float zf = zbuf[tid] + zbuf[tid + 128] + zbuf[tid + 256] + zbuf[tid + 384]
                     + xs[t] * ik_sl[tid] + u * bmk_sl[tid];
            hnew = tanhf(zf);
            __builtin_nontemporal_store(hnew, &outb[(size_t)t * N_UNITS + 128 * q + tid]);
            h_h16[128 * q + tid] = f2h_bits(hnew);
        }

        if (t < N_T - 1) {
            // ---- publish own slices, packed wide (requests: 32 m + 64 h + 2 u) ----
            const u32 eph = (u32)(t + 1) << 16;
            u32* myb = pkt + (size_t)((t & 1) * 256 + b * 4 + q) * PKT_STRIDE;
            if (tid < 64) {     // m: pairs via shfl, dwordx4 from even lanes
                u32 m0 = (u32)mhi_b | eph, m1 = (u32)mlo_b | eph;
                u32 n0 = __shfl_xor(m0, 1), n1 = __shfl_xor(m1, 1);
                if ((jl & 1) == 0) astore4(myb + 2 * jl, m0, m1, n0, n1);
            }
            if (tid < 128) {    // h: pairs via shfl, dwordx2 from even lanes
                u32 hd = (u32)f2h_bits(hnew) | eph;
                u32 hn = __shfl_xor(hd, 1);
                if ((tid & 1) == 0) astore2(myb + 128 + tid, hd, hn);
            }

            // ---- own u-partials for t+1: per-wave reduce, immediate publish ----
            float up = 0.f;
            if (tid < 128) {
                up = hnew * he_sl[tid];
                if (tid < 64) up = fmaf(mnew, me_sl[tid], up);
            }
            #pragma unroll
            for (int off = 32; off > 0; off >>= 1) up += __shfl_down(up, off);
            if (lane == 0 && tid < 128) {
                const int w01 = tid >> 6;
                upw[pc ^ 1][w01] = up;
                _Float16 hi = (_Float16)up;
                float lo = up - (float)hi;
                astore2(myb + 256 + 2 * w01, (u32)__builtin_bit_cast(u16, hi) | eph,
                                             (u32)f2h_bits(lo) | eph);
            }
        }
        // (no B3 — barrier collectivity makes the parity buffers WAR-safe)
    }
}

extern "C" void kernel_launch(void* const* d_in, const int* in_sizes, int n_in,
                              void* d_out, int out_size, void* d_ws, size_t ws_size,
                              hipStream_t stream) {
    const float* x  = (const float*)d_in[0];
    const float* ie = (const float*)d_in[1];
    const float* he = (const float*)d_in[2];
    const float* me = (const float*)d_in[3];
    const float* ik = (const float*)d_in[4];
    const float* hk = (const float*)d_in[5];
    const float* mk = (const float*)d_in[6];
    const float* at = (const float*)d_in[7];
    const float* bt = (const float*)d_in[8];

    u32*   hk2  = (u32*)d_ws;                   // 131072 u32 = 512 KB
    u32*   amk2 = hk2 + 256 * 512;              //  65536 u32 = 256 KB
    float* bmk  = (float*)(amk2 + 128 * 512);   //    512 f32 =   2 KB
    u32*   pkt  = (u32*)(bmk + 512);            // 2*64*4*288 u32 = 576 KB

    prep_hk<<<512, 256, 0, stream>>>(hk, hk2);
    prep_amk<<<129, 512, 0, stream>>>(mk, at, bt, amk2, bmk);
    lmu_main<<<N_B * KWG, 512, 0, stream>>>(x, ie, he, me, ik, bt, at,
                                            hk2, amk2, bmk, pkt, (float*)d_out);
}

// Round 8
// 2675.282 us; speedup vs baseline: 1.1365x; 1.1365x over previous
//
#include <hip/hip_runtime.h>
#include <hip/hip_fp16.h>

typedef unsigned int u32;
typedef unsigned short u16;
typedef _Float16 half2v __attribute__((ext_vector_type(2)));
typedef u32 u32x4 __attribute__((ext_vector_type(4)));
typedef u32 u32x2 __attribute__((ext_vector_type(2)));

#define N_UNITS 512
#define N_ORDER 256
#define N_T     1024
#define N_B     64
#define KWG     4
#define PKT_STRIDE 288   // dwords per (parity,b,q) packet: 128 m + 128 h + 2 u + pad

__device__ inline float dot2f(u32 a, u32 b, float acc) {
    return __builtin_amdgcn_fdot2(__builtin_bit_cast(half2v, a),
                                  __builtin_bit_cast(half2v, b), acc, false);
}
__device__ inline u16 f2h_bits(float v) {
    _Float16 f = (_Float16)v;
    return __builtin_bit_cast(u16, f);
}
__device__ inline float hbits2f(u32 dw) {
    u16 s = (u16)(dw & 0xFFFFu);
    _Float16 f = __builtin_bit_cast(_Float16, s);
    return (float)f;
}
__device__ inline u32 pack_h2(float a, float b) {
    return (u32)f2h_bits(a) | ((u32)f2h_bits(b) << 16);
}
__device__ inline u32 aload(const u32* p) {
    return __hip_atomic_load(p, __ATOMIC_RELAXED, __HIP_MEMORY_SCOPE_AGENT);
}
__device__ inline void astore(u32* p, u32 v) {
    __hip_atomic_store(p, v, __ATOMIC_RELAXED, __HIP_MEMORY_SCOPE_AGENT);
}
// Wide coherent packet ops (R6-proven): ONE line-request at the coherence
// point; per-dword atomicity of aligned dwordx2/x4 is architectural; each
// dword self-validates via the epoch in its high16.
__device__ inline u32x4 aload4(const u32* p) {
    u32x4 r;
    asm volatile("global_load_dwordx4 %0, %1, off sc0 sc1\n\ts_waitcnt vmcnt(0)"
                 : "=&v"(r) : "v"(p) : "memory");
    return r;
}
__device__ inline u32x2 aload2(const u32* p) {
    u32x2 r;
    asm volatile("global_load_dwordx2 %0, %1, off sc0 sc1\n\ts_waitcnt vmcnt(0)"
                 : "=&v"(r) : "v"(p) : "memory");
    return r;
}
__device__ inline void astore2(u32* p, u32 a, u32 b) {
    u32x2 v; v.x = a; v.y = b;
    asm volatile("global_store_dwordx2 %0, %1, off sc0 sc1"
                 :: "v"(p), "v"(v) : "memory");
}

// hk2[kk][c] = half2(hk[2kk][c], hk[2kk+1][c]),  kk<256, c<512
__global__ __launch_bounds__(256)
void prep_hk(const float* __restrict__ hk, u32* __restrict__ hk2) {
    int tid = blockIdx.x * 256 + threadIdx.x;   // 131072 total
    int kk = tid >> 9, c = tid & 511;
    hk2[tid] = pack_h2(hk[(2 * kk) * 512 + c], hk[(2 * kk + 1) * 512 + c]);
}

// AMK = mk + AT@mk  (fp16, j-pair packed);  BMK = BT@mk (fp32)
__global__ __launch_bounds__(512)
void prep_amk(const float* __restrict__ mk, const float* __restrict__ at,
              const float* __restrict__ bt,
              u32* __restrict__ amk2, float* __restrict__ bmk) {
    int bj = blockIdx.x, c = threadIdx.x;
    if (bj < 128) {
        int j0 = 2 * bj, j1 = j0 + 1;
        float a0 = mk[j0 * 512 + c];
        float a1 = mk[j1 * 512 + c];
        #pragma unroll 8
        for (int k = 0; k < 256; ++k) {
            float w = mk[k * 512 + c];
            a0 = fmaf(at[j0 * 256 + k], w, a0);
            a1 = fmaf(at[j1 * 256 + k], w, a1);
        }
        amk2[bj * 512 + c] = pack_h2(a0, a1);
    } else {
        float s = 0.f;
        #pragma unroll 8
        for (int k = 0; k < 256; ++k) s = fmaf(bt[k], mk[k * 512 + c], s);
        bmk[c] = s;
    }
}

// K=4 WGs per batch; grid=256 (1 WG/CU). g: b=g&63, q=g>>6 (same XCD mod-8).
// WG q owns h cols [128q,128q+128), m cols [64q,64q+64).
// Round-8 = R6 (2760us, best verified) + balanced early-compute:
//  * k-split PERMUTED so each thread's dot-range has 16 h-pairs + 8 m-pairs
//    + 8 at-rows in EACH slice quarter.
//  * After finalize(t) publishes + B3, ALL threads compute the own-slice
//    quarter of z/am for t+1 into registers (state t own-slice is in LDS,
//    disjoint from what the next poll overwrites). Post-B1 phase does the
//    3 peer quarters. Work conserved; ~25% of z overlaps the cross-WG RTT.
//  * switch(q) arms keep register-array indices compile-time (no scratch).
__global__ __launch_bounds__(512, 2)
void lmu_main(const float* __restrict__ x, const float* __restrict__ ie,
              const float* __restrict__ he, const float* __restrict__ me,
              const float* __restrict__ ik, const float* __restrict__ bt,
              const float* __restrict__ at,
              const u32* __restrict__ hk2, const u32* __restrict__ amk2,
              const float* __restrict__ bmk,
              u32* __restrict__ pkt, float* __restrict__ out) {
    __shared__ float xs[N_T];
    __shared__ float he_sl[128], ik_sl[128], bmk_sl[128];
    __shared__ float me_sl[64], bt_sl[64];
    __shared__ __align__(8) u16 h_h16[N_UNITS];     // full h, fp16
    __shared__ __align__(8) u16 m_hi16[N_ORDER], m_lo16[N_ORDER];
    __shared__ __align__(8) float mf[N_ORDER];      // full m, fp32(-ish)
    __shared__ float zbuf[512], ampart[512];
    __shared__ float upart[4];                      // u partials per q
    __shared__ float upw[2];

    const int tid = threadIdx.x;
    const int g   = blockIdx.x;
    const int b   = g & 63;
    const int q   = g >> 6;
    const int kg  = tid >> 7;        // 0..3 (hk/AMK k-group)
    const int cl  = tid & 127;       // col within own h slice
    const int kg8 = tid >> 6;        // 0..7 (AT k-group)
    const int jl  = tid & 63;
    const int J   = 64 * q + jl;
    const int lane = tid & 63;

    // ---- preload LDS ----
    for (int i = tid; i < N_T; i += 512) xs[i] = x[b * N_T + i];
    if (tid < 128) {
        he_sl[tid]  = he[128 * q + tid];
        ik_sl[tid]  = ik[128 * q + tid];
        bmk_sl[tid] = bmk[128 * q + tid];
    }
    if (tid < 64) { me_sl[tid] = me[J]; bt_sl[tid] = bt[J]; }
    h_h16[tid] = 0;
    if (tid < 256) { m_hi16[tid] = 0; m_lo16[tid] = 0; mf[tid] = 0.f; }
    if (tid < 4) upart[tid] = 0.f;
    const float ie0 = ie[0];

    // ---- weights into registers (once), slice-permuted k-assignment ----
    // hk_w[16s+i]  <- h-pair  k = 64s + 16kg + i   (16 pairs per slice s)
    // amk_w[8s+i]  <- m-pair  k = 32s + 8kg  + i   ( 8 pairs per slice s)
    // at_w[8s+i]   <- m-row   k = 64s + 8kg8 + i   ( 8 rows  per slice s)
    u32 hk_w[64];
    #pragma unroll
    for (int s = 0; s < 4; ++s)
        #pragma unroll
        for (int i = 0; i < 16; ++i)
            hk_w[16 * s + i] = hk2[(size_t)(64 * s + 16 * kg + i) * 512 + 128 * q + cl];
    u32 amk_w[32];
    #pragma unroll
    for (int s = 0; s < 4; ++s)
        #pragma unroll
        for (int i = 0; i < 8; ++i)
            amk_w[8 * s + i] = amk2[(size_t)(32 * s + 8 * kg + i) * 512 + 128 * q + cl];
    float at_w[32];
    #pragma unroll
    for (int s = 0; s < 4; ++s)
        #pragma unroll
        for (int i = 0; i < 8; ++i)
            at_w[8 * s + i] = at[(size_t)(64 * s + 8 * kg8 + i) * 256 + J];

    __syncthreads();

    const u32* h2u   = reinterpret_cast<const u32*>(h_h16);
    const u32* m_hi2 = reinterpret_cast<const u32*>(m_hi16);
    const u32* m_lo2 = reinterpret_cast<const u32*>(m_lo16);
    float* outb = out + (size_t)b * N_T * N_UNITS;

    float ez = 0.f, eam = 0.f;   // own-slice early partials (for step t)

    for (int t = 0; t < N_T; ++t) {
        // ---- consume peers' packets (h_{t-1}, m_{t-1}, u-partials) ----
        if (t > 0) {
            const u32 ep  = (u32)t;
            const int par = (t - 1) & 1;
            if (tid < 195) {
                int pi = (tid < 192) ? (tid >> 6) : (tid - 192);
                int q2 = pi + (pi >= q ? 1 : 0);
                const u32* base = pkt + (size_t)(par * 256 + b * 4 + q2) * PKT_STRIDE;
                if (tid < 192) {
                    int i = tid & 63;
                    u32 d0, d1, d2, d3;
                    for (;;) {
                        u32x4 dv = aload4(base + 4 * i);
                        d0 = dv.x; d1 = dv.y; d2 = dv.z; d3 = dv.w;
                        if (((((d0 >> 16) ^ ep) | ((d1 >> 16) ^ ep)) |
                             (((d2 >> 16) ^ ep) | ((d3 >> 16) ^ ep))) == 0) break;
                    }
                    if (i < 32) {          // m: j = 2i, 2i+1 (hi,lo dword pairs)
                        int idx = 64 * q2 + 2 * i;
                        mf[idx]         = hbits2f(d0) + hbits2f(d1);
                        m_hi16[idx]     = (u16)d0;  m_lo16[idx]     = (u16)d1;
                        mf[idx + 1]     = hbits2f(d2) + hbits2f(d3);
                        m_hi16[idx + 1] = (u16)d2;  m_lo16[idx + 1] = (u16)d3;
                    } else {               // h: c = 4i-128 .. +3
                        int idx = 128 * q2 + (4 * i - 128);
                        h_h16[idx]     = (u16)d0;
                        h_h16[idx + 1] = (u16)d1;
                        h_h16[idx + 2] = (u16)d2;
                        h_h16[idx + 3] = (u16)d3;
                    }
                } else {                   // u partial (hi/lo dwords, one dwordx2)
                    u32 d0, d1;
                    for (;;) {
                        u32x2 dv = aload2(base + 256);
                        d0 = dv.x; d1 = dv.y;
                        if ((((d0 >> 16) ^ ep) | ((d1 >> 16) ^ ep)) == 0) break;
                    }
                    upart[q2] = hbits2f(d0) + hbits2f(d1);
                }
            }
        }
        __syncthreads();                                   // B1

        // ---- z/am partials: PEER slices only (own quarter already in ez/eam) ----
        {
            float z = ez;
            #pragma unroll
            for (int s = 0; s < 4; ++s) {
                if (s == q) continue;                      // uniform branch
                #pragma unroll
                for (int i = 0; i < 16; ++i)
                    z = dot2f(h2u[64 * s + 16 * kg + i], hk_w[16 * s + i], z);
                #pragma unroll
                for (int i = 0; i < 8; ++i) {
                    u32 wv = amk_w[8 * s + i];
                    z = dot2f(m_hi2[32 * s + 8 * kg + i], wv, z);
                    z = dot2f(m_lo2[32 * s + 8 * kg + i], wv, z);
                }
            }
            zbuf[tid] = z;
            float am = eam;
            #pragma unroll
            for (int s = 0; s < 4; ++s) {
                if (s == q) continue;
                #pragma unroll
                for (int i = 0; i < 8; ++i)
                    am = fmaf(mf[64 * s + 8 * kg8 + i], at_w[8 * s + i], am);
            }
            ampart[tid] = am;
        }
        __syncthreads();                                   // B2

        // ---- finalize: u, m_new slice, h_new slice ----
        float u = 0.f, mnew = 0.f, hnew = 0.f;
        u16 mhi_b = 0, mlo_b = 0;
        if (tid < 128)
            u = upart[0] + upart[1] + upart[2] + upart[3] + xs[t] * ie0;
        if (tid < 64) {
            mnew = mf[J] + u * bt_sl[tid];
            #pragma unroll
            for (int gi = 0; gi < 8; ++gi) mnew += ampart[tid + 64 * gi];
            _Float16 hi = (_Float16)mnew;
            float lo = mnew - (float)hi;
            mhi_b = __builtin_bit_cast(u16, hi);
            mlo_b = f2h_bits(lo);
            mf[J] = mnew;            // own slice stays exact fp32
            m_hi16[J] = mhi_b;
            m_lo16[J] = mlo_b;
        }
        if (tid < 128) {
            float zf = zbuf[tid] + zbuf[tid + 128] + zbuf[tid + 256] + zbuf[tid + 384]
                     + xs[t] * ik_sl[tid] + u * bmk_sl[tid];
            hnew = tanhf(zf);
            __builtin_nontemporal_store(hnew, &outb[(size_t)t * N_UNITS + 128 * q + tid]);
            h_h16[128 * q + tid] = f2h_bits(hnew);
        }

        if (t < N_T - 1) {
            // ---- publish own slices (R6-proven wide stores) ----
            const u32 eph = (u32)(t + 1) << 16;
            u32* myb = pkt + (size_t)((t & 1) * 256 + b * 4 + q) * PKT_STRIDE;
            if (tid < 64)
                astore2(myb + 2 * tid, (u32)mhi_b | eph, (u32)mlo_b | eph);
            if (tid < 128)
                astore(myb + 128 + tid, (u32)f2h_bits(hnew) | eph);

            // ---- own u-partial for step t+1 (R6 funnel) ----
            float up = 0.f;
            if (tid < 128) {
                up = hnew * he_sl[tid];
                if (tid < 64) up = fmaf(mnew, me_sl[tid], up);
            }
            #pragma unroll
            for (int off = 32; off > 0; off >>= 1) up += __shfl_down(up, off);
            if (lane == 0 && tid < 128) upw[tid >> 6] = up;
            __syncthreads();                               // B3
            if (tid == 0) {
                float myu = upw[0] + upw[1];
                upart[q] = myu;
                _Float16 hi = (_Float16)myu;
                float lo = myu - (float)hi;
                astore2(myb + 256, (u32)__builtin_bit_cast(u16, hi) | eph,
                                   (u32)f2h_bits(lo) | eph);
            }

            // ---- EARLY: own-slice quarter of z/am for t+1 (overlaps peers' RTT)
            // own state(t) slices are in LDS (ordered by B3); disjoint from the
            // regions the next poll overwrites. Register indices compile-time.
            #define EARLY_CHUNK(SQ)                                              \
            {                                                                    \
                float e = 0.f, ea = 0.f;                                         \
                _Pragma("unroll")                                                \
                for (int i = 0; i < 16; ++i)                                     \
                    e = dot2f(h2u[64 * (SQ) + 16 * kg + i],                      \
                              hk_w[16 * (SQ) + i], e);                           \
                _Pragma("unroll")                                                \
                for (int i = 0; i < 8; ++i) {                                    \
                    u32 wv = amk_w[8 * (SQ) + i];                                \
                    e = dot2f(m_hi2[32 * (SQ) + 8 * kg + i], wv, e);             \
                    e = dot2f(m_lo2[32 * (SQ) + 8 * kg + i], wv, e);             \
                }                                                                \
                _Pragma("unroll")                                                \
                for (int i = 0; i < 8; ++i)                                      \
                    ea = fmaf(mf[64 * (SQ) + 8 * kg8 + i],                       \
                              at_w[8 * (SQ) + i], ea);                           \
                ez = e; eam = ea;                                                \
            }
            switch (q) {
                case 0:  EARLY_CHUNK(0); break;
                case 1:  EARLY_CHUNK(1); break;
                case 2:  EARLY_CHUNK(2); break;
                default: EARLY_CHUNK(3); break;
            }
            #undef EARLY_CHUNK
        }
    }
}

extern "C" void kernel_launch(void* const* d_in, const int* in_sizes, int n_in,
                              void* d_out, int out_size, void* d_ws, size_t ws_size,
                              hipStream_t stream) {
    const float* x  = (const float*)d_in[0];
    const float* ie = (const float*)d_in[1];
    const float* he = (const float*)d_in[2];
    const float* me = (const float*)d_in[3];
    const float* ik = (const float*)d_in[4];
    const float* hk = (const float*)d_in[5];
    const float* mk = (const float*)d_in[6];
    const float* at = (const float*)d_in[7];
    const float* bt = (const float*)d_in[8];

    u32*   hk2  = (u32*)d_ws;                   // 131072 u32 = 512 KB
    u32*   amk2 = hk2 + 256 * 512;              //  65536 u32 = 256 KB
    float* bmk  = (float*)(amk2 + 128 * 512);   //    512 f32 =   2 KB
    u32*   pkt  = (u32*)(bmk + 512);            // 2*64*4*288 u32 = 576 KB

    prep_hk<<<512, 256, 0, stream>>>(hk, hk2);
    prep_amk<<<129, 512, 0, stream>>>(mk, at, bt, amk2, bmk);
    lmu_main<<<N_B * KWG, 512, 0, stream>>>(x, ie, he, me, ik, bt, at,
                                            hk2, amk2, bmk, pkt, (float*)d_out);
}